// Round 2
// baseline (595.567 us; speedup 1.0000x reference)
//
#include <hip/hip_runtime.h>
#include <hip/hip_bf16.h>

// CAPMemory loss on MI355X — round 2.
//   K1 prep:  fn = normalize(features); nrows = normalize(0.01*old+0.99*f); fnb = bf16(fn)
//   K2 gemm:  sims[256][32768] = fn @ mem0^T (bf16 MFMA, fp32 acc, reg-double-buffered
//             staging so kit+1 global loads overlap kit MFMA; mem0 HBM-read exactly once)
//   K3 dots:  sdot_all[256][32] = fp32 fn_i . nrows_j (camera block) — CE correction dots
//   K4 fused: per row: CE lse over diag block (target swapped to corrected dot) +
//             cross-camera exact top-50 via 12-bit histogram + wave-parallel boundary
//             select; single atomicAdd per row.
// mem0 rows are unit-norm by construction; renorm is ~1e-7 perturbation -> skipped.

#define Dn 2048
#define Ln 4096
#define Cn 8
#define Bn 256
#define NTOT 32768
#define INVB 20.0f
#define KNN 50

typedef __attribute__((ext_vector_type(8))) short short8;
typedef __attribute__((ext_vector_type(4))) float f32x4;

__device__ __forceinline__ unsigned short f2b(float f) {
    unsigned u = __float_as_uint(f);
    unsigned r = (u + 0x7FFFu + ((u >> 16) & 1u)) >> 16;   // RNE
    return (unsigned short)r;
}

__device__ __forceinline__ unsigned pack2(float x, float y) {
    __hip_bfloat162 h = __float22bfloat162_rn(float2{x, y});
    unsigned u; __builtin_memcpy(&u, &h, 4); return u;     // [bf(x),bf(y)] low,high
}

// ---------------- K1: prep ----------------
__global__ __launch_bounds__(256) void prep_kernel(
    const float* __restrict__ feat, const float* __restrict__ mem0,
    const int* __restrict__ targets, const int* __restrict__ cams,
    float* __restrict__ fn, float* __restrict__ nrows,
    unsigned short* __restrict__ fnb) {
    int i = blockIdx.x, tid = threadIdx.x;
    int c = cams[i], t = targets[i];
    const float* f = feat + (size_t)i * Dn;
    const float* o = mem0 + ((size_t)c * Ln + t) * Dn;
    float fv[8], nv[8];
    float s1 = 0.f, s2 = 0.f;
#pragma unroll
    for (int r = 0; r < 8; ++r) {
        int idx = tid + (r << 8);
        float a = f[idx], b = o[idx];
        float n = 0.99f * a + 0.01f * b;
        fv[r] = a; nv[r] = n;
        s1 += a * a; s2 += n * n;
    }
    __shared__ float red[2][4];
    for (int off = 32; off > 0; off >>= 1) {
        s1 += __shfl_down(s1, off);
        s2 += __shfl_down(s2, off);
    }
    int wv = tid >> 6;
    if ((tid & 63) == 0) { red[0][wv] = s1; red[1][wv] = s2; }
    __syncthreads();
    s1 = red[0][0] + red[0][1] + red[0][2] + red[0][3];
    s2 = red[1][0] + red[1][1] + red[1][2] + red[1][3];
    float r1 = 1.0f / sqrtf(s1), r2 = 1.0f / sqrtf(s2);
#pragma unroll
    for (int r = 0; r < 8; ++r) {
        int idx = tid + (r << 8);
        float a = fv[r] * r1;
        fn[(size_t)i * Dn + idx] = a;
        fnb[(size_t)i * Dn + idx] = f2b(a);
        nrows[(size_t)i * Dn + idx] = nv[r] * r2;
    }
}

// ---------------- K2: sims = fn @ mem0^T (bf16 MFMA, reg-pipelined) ----------------
// Tile M=256 x N=64, BK=64. LDS rows padded +8 shorts (stride 144B: 2-way = free).
__global__ __launch_bounds__(256, 2) void gemm_sims(
    const float* __restrict__ mem0, const unsigned short* __restrict__ fnb,
    float* __restrict__ sims) {
    __shared__ __align__(16) unsigned short lA[256 * 72];
    __shared__ __align__(16) unsigned short lB[64 * 72];
    int tid = threadIdx.x;
    int n0 = blockIdx.x * 64;
    int lane = tid & 63, wv = tid >> 6;
    int fr = lane & 15, fg = lane >> 4;
    f32x4 acc[4][4];
#pragma unroll
    for (int a = 0; a < 4; ++a)
#pragma unroll
        for (int b = 0; b < 4; ++b)
#pragma unroll
            for (int k = 0; k < 4; ++k) acc[a][b][k] = 0.0f;
    int atr = tid >> 3, atc = tid & 7;     // A staging: 8 thr/row, 16B each
    int btr = tid >> 4, btc = tid & 15;    // B staging: 16 thr/row, float4 each

    int4 ra[8]; float4 rb[4];
#pragma unroll
    for (int r = 0; r < 8; ++r)
        ra[r] = *(const int4*)&fnb[(size_t)(r * 32 + atr) * Dn + atc * 8];
#pragma unroll
    for (int r = 0; r < 4; ++r)
        rb[r] = *(const float4*)&mem0[(size_t)(n0 + r * 16 + btr) * Dn + btc * 4];

    for (int kit = 0; kit < 32; ++kit) {
        // stage prefetched regs -> LDS (compiler waits vmcnt here)
#pragma unroll
        for (int r = 0; r < 8; ++r)
            *(int4*)&lA[(r * 32 + atr) * 72 + atc * 8] = ra[r];
#pragma unroll
        for (int r = 0; r < 4; ++r) {
            float4 v = rb[r];
            uint2 h; h.x = pack2(v.x, v.y); h.y = pack2(v.z, v.w);
            *(uint2*)&lB[(r * 16 + btr) * 72 + btc * 4] = h;
        }
        __syncthreads();
        // prefetch kit+1 while MFMAs run on this tile
        if (kit + 1 < 32) {
#pragma unroll
            for (int r = 0; r < 8; ++r)
                ra[r] = *(const int4*)&fnb[(size_t)(r * 32 + atr) * Dn + (kit + 1) * 64 + atc * 8];
#pragma unroll
            for (int r = 0; r < 4; ++r)
                rb[r] = *(const float4*)&mem0[(size_t)(n0 + r * 16 + btr) * Dn + (kit + 1) * 64 + btc * 4];
        }
#pragma unroll
        for (int kb = 0; kb < 2; ++kb) {
            short8 av[4], bv[4];
#pragma unroll
            for (int mf = 0; mf < 4; ++mf)
                av[mf] = *(const short8*)&lA[(wv * 64 + mf * 16 + fr) * 72 + kb * 32 + fg * 8];
#pragma unroll
            for (int nf = 0; nf < 4; ++nf)
                bv[nf] = *(const short8*)&lB[(nf * 16 + fr) * 72 + kb * 32 + fg * 8];
#pragma unroll
            for (int mf = 0; mf < 4; ++mf)
#pragma unroll
                for (int nf = 0; nf < 4; ++nf)
                    acc[mf][nf] = __builtin_amdgcn_mfma_f32_16x16x32_bf16(
                        av[mf], bv[nf], acc[mf][nf], 0, 0, 0);
        }
        __syncthreads();
    }
    // C/D layout (m89): col = lane&15 (N), row = (lane>>4)*4 + reg (M)
#pragma unroll
    for (int mf = 0; mf < 4; ++mf)
#pragma unroll
        for (int nf = 0; nf < 4; ++nf)
#pragma unroll
            for (int r = 0; r < 4; ++r) {
                int m = wv * 64 + mf * 16 + fg * 4 + r;
                int n = n0 + nf * 16 + fr;
                sims[(size_t)m * NTOT + n] = acc[mf][nf][r];
            }
}

// ---------------- K3: fp32 correction dots ----------------
__global__ __launch_bounds__(256) void dots_kernel(
    const float* __restrict__ fn, const float* __restrict__ nrows,
    float* __restrict__ sdot_all) {
    int i = blockIdx.x, tid = threadIdx.x;
    int lane = tid & 63, wv = tid >> 6;
    int c = i >> 5;
    float f[32];
    const float* frp = fn + (size_t)i * Dn;
#pragma unroll
    for (int r = 0; r < 32; ++r) f[r] = frp[lane + (r << 6)];
    for (int jj = 0; jj < 8; ++jj) {
        int j = wv * 8 + jj;
        const float* nr = nrows + (size_t)(c * 32 + j) * Dn;
        float d = 0.f;
#pragma unroll
        for (int r = 0; r < 32; ++r) d += f[r] * nr[lane + (r << 6)];
        for (int o = 32; o > 0; o >>= 1) d += __shfl_down(d, o);
        if (lane == 0) sdot_all[i * 32 + j] = d;
    }
}

// ---------------- K4: fused CE + cross-camera loss ----------------
__global__ __launch_bounds__(256) void fused_kernel(
    const float* __restrict__ sims, const float* __restrict__ sdot_all,
    const int* __restrict__ targets, float* __restrict__ out) {
    __shared__ int hist[4][4096];
    __shared__ int ghist[256];
    __shared__ float buf[1024];
    __shared__ int cnt;
    __shared__ int sh_bstar, sh_r;
    __shared__ float wsum[4], cesum[4];
    int i = blockIdx.x, tid = threadIdx.x;
    int wv = tid >> 6, lane = tid & 63;
    int t = targets[i];
    int c = i >> 5, b = i & 31;
    const float* row = sims + (size_t)i * NTOT;
    for (int k = tid; k < 4 * 4096; k += 256) ((int*)hist)[k] = 0;
    if (tid == 0) cnt = 0;
    __syncthreads();
    // pass 1: histogram (masked skipped) + CE diag exp-sum (all diag positions)
    float ce_p = 0.f;
    for (int q = 0; q < 128; ++q) {
        int j = tid + (q << 8);
        float v = row[j];
        if ((j >> 12) == c) ce_p += expf(v * INVB);
        if ((j & (Ln - 1)) != t) {
            unsigned u = __float_as_uint(v);
            unsigned key = (u & 0x80000000u) ? ~u : (u | 0x80000000u);
            atomicAdd(&hist[wv][key >> 20], 1);
        }
    }
    for (int o = 32; o > 0; o >>= 1) ce_p += __shfl_down(ce_p, o);
    if (lane == 0) cesum[wv] = ce_p;
    __syncthreads();
    for (int k = tid; k < 4096; k += 256)
        hist[0][k] = hist[0][k] + hist[1][k] + hist[2][k] + hist[3][k];
    __syncthreads();
    {
        int s = 0;
#pragma unroll
        for (int k = 0; k < 16; ++k) s += hist[0][tid * 16 + k];
        ghist[tid] = s;
    }
    __syncthreads();
    if (tid == 0) {
        int cum = 0, g = 255;
        for (; g > 0; --g) { if (cum + ghist[g] >= KNN) break; cum += ghist[g]; }
        int bb = g * 16 + 15;
        for (;; --bb) { int h = hist[0][bb]; if (cum + h >= KNN) break; cum += h; }
        sh_bstar = bb;
        sh_r = KNN - cum;
    }
    __syncthreads();
    int bstar = sh_bstar;
    // pass 2: exp-sum of strictly-above bins; collect boundary-bin values
    float lsum = 0.f;
    for (int q = 0; q < 128; ++q) {
        int j = tid + (q << 8);
        if ((j & (Ln - 1)) == t) continue;
        float v = row[j];
        unsigned u = __float_as_uint(v);
        unsigned key = (u & 0x80000000u) ? ~u : (u | 0x80000000u);
        int bin = key >> 20;
        if (bin > bstar) {
            lsum += expf(v * INVB);
        } else if (bin == bstar) {
            int p = atomicAdd(&cnt, 1);
            if (p < 1024) buf[p] = v;
        }
    }
    for (int o = 32; o > 0; o >>= 1) lsum += __shfl_down(lsum, o);
    if (lane == 0) wsum[wv] = lsum;
    __syncthreads();
    if (wv == 0) {
        // wave-parallel exact top-r of boundary bin
        int nb = min(cnt, 1024);
        int r = sh_r;
        float bsum = 0.f;   // lane 0 accumulates
        for (int s = 0; s < r; ++s) {
            float mv = -3e38f; int mi = 0;
            for (int k = lane; k < nb; k += 64) {
                float v = buf[k];
                if (v > mv) { mv = v; mi = k; }
            }
            for (int o = 32; o > 0; o >>= 1) {
                float ov = __shfl_down(mv, o);
                int oi = __shfl_down(mi, o);
                if (ov > mv) { mv = ov; mi = oi; }
            }
            mi = __shfl(mi, 0); mv = __shfl(mv, 0);
            if (lane == 0) { buf[mi] = -3e38f; bsum += expf(mv * INVB); }
            __builtin_amdgcn_wave_barrier();
        }
        if (lane == 0) {
            float S = wsum[0] + wsum[1] + wsum[2] + wsum[3] + bsum;
            float psum = 0.f, pls = 0.f;
#pragma unroll
            for (int c2 = 0; c2 < Cn; ++c2) {
                float pv = row[t + c2 * Ln] * INVB;
                psum += expf(pv);
                pls += pv;
            }
            S += psum;
            float per = logf(S) - pls * (1.0f / Cn);
            // CE: swap masked diag target for corrected fp32 dot
            float sd = sdot_all[i * 32 + b];
            float Sce = cesum[0] + cesum[1] + cesum[2] + cesum[3]
                        - expf(row[(c << 12) + t] * INVB) + expf(sd * INVB);
            float ce = logf(Sce) - sd * INVB;
            atomicAdd(out, ce * (1.0f / 32.0f) + 0.5f * per * (1.0f / 32.0f));
        }
    }
}

extern "C" void kernel_launch(void* const* d_in, const int* in_sizes, int n_in,
                              void* d_out, int out_size, void* d_ws, size_t ws_size,
                              hipStream_t stream) {
    const float* feat    = (const float*)d_in[0];
    const int*   targets = (const int*)d_in[1];
    const int*   cams    = (const int*)d_in[2];
    const float* mem0    = (const float*)d_in[5];
    float* out = (float*)d_out;
    char* ws = (char*)d_ws;
    float*          fn    = (float*)(ws);                              // 2 MB
    float*          nrows = (float*)(ws + (size_t)(2 << 20));          // 2 MB
    unsigned short* fnb   = (unsigned short*)(ws + (size_t)(4 << 20)); // 1 MB
    float*          sdot  = (float*)(ws + (size_t)(6 << 20));          // 32 KB
    float*          sims  = (float*)(ws + (size_t)(8 << 20));          // 32 MB

    hipMemsetAsync(d_out, 0, (size_t)out_size * sizeof(float), stream);
    prep_kernel<<<Bn, 256, 0, stream>>>(feat, mem0, targets, cams, fn, nrows, fnb);
    gemm_sims<<<NTOT / 64, 256, 0, stream>>>(mem0, fnb, sims);
    dots_kernel<<<Bn, 256, 0, stream>>>(fn, nrows, sdot);
    fused_kernel<<<Bn, 256, 0, stream>>>(sims, sdot, targets, out);
}

// Round 3
// 506.123 us; speedup vs baseline: 1.1767x; 1.1767x over previous
//
#include <hip/hip_runtime.h>
#include <hip/hip_bf16.h>

// CAPMemory loss on MI355X — round 3.
//   K1 prep:  fn = normalize(features); nrows = normalize(0.01*old+0.99*f); fnb = bf16(fn)
//   K2 gemm:  sims[256][32768] = fn @ mem0^T. A (fnb, 1MB, L2-hot) loaded as MFMA
//             fragments DIRECTLY from global (no LDS); B (mem0 HBM stream) through
//             double-buffered LDS with distance-2 register prefetch; 1 barrier/kit.
//             Epilogue transposes acc via LDS -> dwordx4 full-line stores.
//   K3 dots:  sdot_all[256][32] = fp32 fn_i . nrows_j — CE correction dots
//   K4 fused: CE lse (target swapped to corrected dot) + cross-camera exact top-50
//             via adaptive value-threshold histogram (atomics only on ~2% tail).
// mem0 rows are unit-norm by construction; renorm is ~1e-7 perturbation -> skipped.

#define Dn 2048
#define Ln 4096
#define Cn 8
#define Bn 256
#define NTOT 32768
#define INVB 20.0f
#define KNN 50

typedef __attribute__((ext_vector_type(8))) short short8;
typedef __attribute__((ext_vector_type(4))) float f32x4;

__device__ __forceinline__ unsigned short f2b(float f) {
    unsigned u = __float_as_uint(f);
    unsigned r = (u + 0x7FFFu + ((u >> 16) & 1u)) >> 16;   // RNE
    return (unsigned short)r;
}

__device__ __forceinline__ unsigned pack2(float x, float y) {
    __hip_bfloat162 h = __float22bfloat162_rn(float2{x, y});
    unsigned u; __builtin_memcpy(&u, &h, 4); return u;
}

// ---------------- K1: prep ----------------
__global__ __launch_bounds__(256) void prep_kernel(
    const float* __restrict__ feat, const float* __restrict__ mem0,
    const int* __restrict__ targets, const int* __restrict__ cams,
    float* __restrict__ fn, float* __restrict__ nrows,
    unsigned short* __restrict__ fnb) {
    int i = blockIdx.x, tid = threadIdx.x;
    int c = cams[i], t = targets[i];
    const float* f = feat + (size_t)i * Dn;
    const float* o = mem0 + ((size_t)c * Ln + t) * Dn;
    float fv[8], nv[8];
    float s1 = 0.f, s2 = 0.f;
#pragma unroll
    for (int r = 0; r < 8; ++r) {
        int idx = tid + (r << 8);
        float a = f[idx], bb = o[idx];
        float n = 0.99f * a + 0.01f * bb;
        fv[r] = a; nv[r] = n;
        s1 += a * a; s2 += n * n;
    }
    __shared__ float red[2][4];
    for (int off = 32; off > 0; off >>= 1) {
        s1 += __shfl_down(s1, off);
        s2 += __shfl_down(s2, off);
    }
    int wv = tid >> 6;
    if ((tid & 63) == 0) { red[0][wv] = s1; red[1][wv] = s2; }
    __syncthreads();
    s1 = red[0][0] + red[0][1] + red[0][2] + red[0][3];
    s2 = red[1][0] + red[1][1] + red[1][2] + red[1][3];
    float r1 = 1.0f / sqrtf(s1), r2 = 1.0f / sqrtf(s2);
#pragma unroll
    for (int r = 0; r < 8; ++r) {
        int idx = tid + (r << 8);
        float a = fv[r] * r1;
        fn[(size_t)i * Dn + idx] = a;
        fnb[(size_t)i * Dn + idx] = f2b(a);
        nrows[(size_t)i * Dn + idx] = nv[r] * r2;
    }
}

// ---------------- K2: sims = fn @ mem0^T ----------------
// M=256 x N=64 per block, BK=64, 32 kits. A direct-from-global fragments
// (prefetch dist 1, L2); B LDS double-buffer (prefetch dist 2, HBM).
#define GSTEP(KIT, CUR, NXT)                                                      \
  {                                                                               \
    if ((KIT) + 1 < 32) {                                                         \
      _Pragma("unroll") for (int mf = 0; mf < 4; ++mf)                            \
        _Pragma("unroll") for (int kb = 0; kb < 2; ++kb)                          \
          av[NXT][mf][kb] =                                                       \
            *(const short8*)&fnb[aoff[mf] + ((KIT) + 1) * 64 + kb * 32];          \
    }                                                                             \
    if ((KIT) + 2 < 32) {                                                         \
      _Pragma("unroll") for (int r = 0; r < 4; ++r)                               \
        rb[CUR][r] = *(const float4*)&mem0[boff[r] + ((KIT) + 2) * 64];           \
    }                                                                             \
    _Pragma("unroll") for (int kb = 0; kb < 2; ++kb) {                            \
      short8 bv[4];                                                               \
      _Pragma("unroll") for (int nf = 0; nf < 4; ++nf)                            \
        bv[nf] = *(const short8*)&lB[CUR][(nf * 16 + fr) * 72 + kb * 32 + fg * 8];\
      _Pragma("unroll") for (int mf = 0; mf < 4; ++mf)                            \
        _Pragma("unroll") for (int nf = 0; nf < 4; ++nf)                          \
          acc[mf][nf] = __builtin_amdgcn_mfma_f32_16x16x32_bf16(                  \
              av[CUR][mf][kb], bv[nf], acc[mf][nf], 0, 0, 0);                     \
    }                                                                             \
    if ((KIT) + 1 < 32) {                                                         \
      _Pragma("unroll") for (int r = 0; r < 4; ++r) {                             \
        float4 v = rb[NXT][r];                                                    \
        uint2 h; h.x = pack2(v.x, v.y); h.y = pack2(v.z, v.w);                    \
        *(uint2*)&lB[NXT][(r * 16 + btr) * 72 + btc * 4] = h;                     \
      }                                                                           \
    }                                                                             \
    __syncthreads();                                                              \
  }

__global__ __launch_bounds__(256, 2) void gemm_sims(
    const float* __restrict__ mem0, const unsigned short* __restrict__ fnb,
    float* __restrict__ sims) {
    __shared__ __align__(16) unsigned short lB[2][64 * 72];
    int tid = threadIdx.x;
    int n0 = blockIdx.x * 64;
    int lane = tid & 63, wv = tid >> 6;
    int fr = lane & 15, fg = lane >> 4;
    int btr = tid >> 4, btc = tid & 15;

    f32x4 acc[4][4];
#pragma unroll
    for (int a = 0; a < 4; ++a)
#pragma unroll
        for (int b = 0; b < 4; ++b)
#pragma unroll
            for (int k = 0; k < 4; ++k) acc[a][b][k] = 0.0f;

    size_t aoff[4], boff[4];
#pragma unroll
    for (int mf = 0; mf < 4; ++mf)
        aoff[mf] = (size_t)(wv * 64 + mf * 16 + fr) * Dn + fg * 8;
#pragma unroll
    for (int r = 0; r < 4; ++r)
        boff[r] = (size_t)(n0 + r * 16 + btr) * Dn + btc * 4;

    float4 rb[2][4];
    short8 av[2][4][2];
    // prologue: B(0)->rb0, B(1)->rb1, A(0)->av0; stage B(0) into lB[0]
#pragma unroll
    for (int r = 0; r < 4; ++r) rb[0][r] = *(const float4*)&mem0[boff[r]];
#pragma unroll
    for (int r = 0; r < 4; ++r) rb[1][r] = *(const float4*)&mem0[boff[r] + 64];
#pragma unroll
    for (int mf = 0; mf < 4; ++mf)
#pragma unroll
        for (int kb = 0; kb < 2; ++kb)
            av[0][mf][kb] = *(const short8*)&fnb[aoff[mf] + kb * 32];
#pragma unroll
    for (int r = 0; r < 4; ++r) {
        float4 v = rb[0][r];
        uint2 h; h.x = pack2(v.x, v.y); h.y = pack2(v.z, v.w);
        *(uint2*)&lB[0][(r * 16 + btr) * 72 + btc * 4] = h;
    }
    __syncthreads();

    for (int k2 = 0; k2 < 16; ++k2) {
        GSTEP(2 * k2, 0, 1);
        GSTEP(2 * k2 + 1, 1, 0);
    }

    // epilogue: per-wave LDS transpose (stride 68 dwords) -> dwordx4 stores
    float* tbuf = (float*)lB;
    int row16 = lane & 15, seg = lane >> 4;
#pragma unroll
    for (int mf = 0; mf < 4; ++mf) {
#pragma unroll
        for (int nf = 0; nf < 4; ++nf)
#pragma unroll
            for (int r = 0; r < 4; ++r)
                tbuf[wv * 1088 + (fg * 4 + r) * 68 + nf * 16 + fr] = acc[mf][nf][r];
        __syncthreads();
#pragma unroll
        for (int q = 0; q < 4; ++q) {
            float4 v = *(float4*)&tbuf[wv * 1088 + row16 * 68 + seg * 16 + q * 4];
            int m = wv * 64 + mf * 16 + row16;
            *(float4*)&sims[(size_t)m * NTOT + n0 + seg * 16 + q * 4] = v;
        }
        __syncthreads();
    }
}

// ---------------- K3: fp32 correction dots ----------------
__global__ __launch_bounds__(256) void dots_kernel(
    const float* __restrict__ fn, const float* __restrict__ nrows,
    float* __restrict__ sdot_all) {
    int i = blockIdx.x, tid = threadIdx.x;
    int lane = tid & 63, wv = tid >> 6;
    int c = i >> 5;
    float f[32];
    const float* frp = fn + (size_t)i * Dn;
#pragma unroll
    for (int r = 0; r < 32; ++r) f[r] = frp[lane + (r << 6)];
    for (int jj = 0; jj < 8; ++jj) {
        int j = wv * 8 + jj;
        const float* nr = nrows + (size_t)(c * 32 + j) * Dn;
        float d = 0.f;
#pragma unroll
        for (int r = 0; r < 32; ++r) d += f[r] * nr[lane + (r << 6)];
        for (int o = 32; o > 0; o >>= 1) d += __shfl_down(d, o);
        if (lane == 0) sdot_all[i * 32 + j] = d;
    }
}

// ---------------- K4: fused CE + cross-camera (adaptive threshold top-k) ------
__global__ __launch_bounds__(256) void fused_kernel(
    const float* __restrict__ sims, const float* __restrict__ sdot_all,
    const int* __restrict__ targets, float* __restrict__ out) {
    __shared__ int hist[4][1024];
    __shared__ int ghist[64];
    __shared__ float buf[512];
    __shared__ int cnt, sh_bstar, sh_r, sh_total;
    __shared__ float wred[4], wmax4[4], wmin4[4], cesum[4];
    int i = blockIdx.x, tid = threadIdx.x;
    int wv = tid >> 6, lane = tid & 63;
    int t = targets[i], c = i >> 5, b = i & 31;
    const float* row = sims + (size_t)i * NTOT;

    // pass A: row max/min (unmasked) + CE diag exp-sum
    float mx = -3e38f, mn = 3e38f, ce_p = 0.f;
    for (int q = 0; q < 128; ++q) {
        int j = tid + (q << 8);
        float v = row[j];
        if ((j >> 12) == c) ce_p += expf(v * INVB);
        if ((j & (Ln - 1)) != t) { mx = fmaxf(mx, v); mn = fminf(mn, v); }
    }
    for (int o = 32; o > 0; o >>= 1) {
        ce_p += __shfl_down(ce_p, o);
        mx = fmaxf(mx, __shfl_down(mx, o));
        mn = fminf(mn, __shfl_down(mn, o));
    }
    if (lane == 0) { cesum[wv] = ce_p; wmax4[wv] = mx; wmin4[wv] = mn; }
    __syncthreads();
    float hi = fmaxf(fmaxf(wmax4[0], wmax4[1]), fmaxf(wmax4[2], wmax4[3]));
    float lo = fminf(fminf(wmin4[0], wmin4[1]), fminf(wmin4[2], wmin4[3]));
    float rng = fmaxf(hi - lo, 1e-30f);

    // adaptive threshold: count tail into 1024 linear bins; widen if < KNN
    float thr = 0.f, scale = 0.f;
    for (int att = 0; att < 3; ++att) {
        float frac = (att == 0) ? 0.25f : ((att == 1) ? 0.5f : 1.0001f);
        thr = hi - rng * frac;
        scale = 1023.0f / fmaxf(hi - thr, 1e-30f);
        for (int k = tid; k < 4096; k += 256) ((int*)hist)[k] = 0;
        __syncthreads();
        for (int q = 0; q < 128; ++q) {
            int j = tid + (q << 8);
            float v = row[j];
            if (v > thr && (j & (Ln - 1)) != t) {
                int bin = min(1023, (int)((v - thr) * scale));
                atomicAdd(&hist[wv][bin], 1);
            }
        }
        __syncthreads();
        for (int k = tid; k < 1024; k += 256)
            hist[0][k] = hist[0][k] + hist[1][k] + hist[2][k] + hist[3][k];
        __syncthreads();
        if (tid < 64) {
            int s = 0;
#pragma unroll
            for (int k = 0; k < 16; ++k) s += hist[0][tid * 16 + k];
            ghist[tid] = s;
        }
        __syncthreads();
        if (tid == 0) {
            int total = 0;
            for (int g = 0; g < 64; ++g) total += ghist[g];
            sh_total = total;
            if (total >= KNN) {
                int cum = 0, g = 63;
                for (; g > 0; --g) { if (cum + ghist[g] >= KNN) break; cum += ghist[g]; }
                int bb = g * 16 + 15;
                for (;; --bb) { int h = hist[0][bb]; if (cum + h >= KNN) break; cum += h; }
                sh_bstar = bb;
                sh_r = KNN - cum;
            }
        }
        __syncthreads();
        if (sh_total >= KNN) break;
        __syncthreads();
    }
    int bstar = sh_bstar;
    if (tid == 0) cnt = 0;
    __syncthreads();
    // pass C: exp-sum of bins above bstar; collect boundary-bin values
    float lsum = 0.f;
    for (int q = 0; q < 128; ++q) {
        int j = tid + (q << 8);
        float v = row[j];
        if (v <= thr || (j & (Ln - 1)) == t) continue;
        int bin = min(1023, (int)((v - thr) * scale));
        if (bin > bstar) {
            lsum += expf(v * INVB);
        } else if (bin == bstar) {
            int p = atomicAdd(&cnt, 1);
            if (p < 512) buf[p] = v;
        }
    }
    for (int o = 32; o > 0; o >>= 1) lsum += __shfl_down(lsum, o);
    if (lane == 0) wred[wv] = lsum;
    __syncthreads();
    if (wv == 0) {
        int nb = min(cnt, 512);
        int r = sh_r;
        float bsum = 0.f;
        for (int s = 0; s < r; ++s) {
            float mv = -3e38f; int mi = 0;
            for (int k = lane; k < nb; k += 64) {
                float v = buf[k];
                if (v > mv) { mv = v; mi = k; }
            }
            for (int o = 32; o > 0; o >>= 1) {
                float ov = __shfl_down(mv, o);
                int oi = __shfl_down(mi, o);
                if (ov > mv) { mv = ov; mi = oi; }
            }
            mi = __shfl(mi, 0); mv = __shfl(mv, 0);
            if (lane == 0) { buf[mi] = -3e38f; bsum += expf(mv * INVB); }
            __builtin_amdgcn_wave_barrier();
        }
        if (lane == 0) {
            float S = wred[0] + wred[1] + wred[2] + wred[3] + bsum;
            float psum = 0.f, pls = 0.f;
#pragma unroll
            for (int c2 = 0; c2 < Cn; ++c2) {
                float pv = row[t + c2 * Ln] * INVB;
                psum += expf(pv);
                pls += pv;
            }
            S += psum;
            float per = logf(S) - pls * (1.0f / Cn);
            float sd = sdot_all[i * 32 + b];
            float Sce = cesum[0] + cesum[1] + cesum[2] + cesum[3]
                        - expf(row[(c << 12) + t] * INVB) + expf(sd * INVB);
            float ce = logf(Sce) - sd * INVB;
            atomicAdd(out, ce * (1.0f / 32.0f) + 0.5f * per * (1.0f / 32.0f));
        }
    }
}

extern "C" void kernel_launch(void* const* d_in, const int* in_sizes, int n_in,
                              void* d_out, int out_size, void* d_ws, size_t ws_size,
                              hipStream_t stream) {
    const float* feat    = (const float*)d_in[0];
    const int*   targets = (const int*)d_in[1];
    const int*   cams    = (const int*)d_in[2];
    const float* mem0    = (const float*)d_in[5];
    float* out = (float*)d_out;
    char* ws = (char*)d_ws;
    float*          fn    = (float*)(ws);                              // 2 MB
    float*          nrows = (float*)(ws + (size_t)(2 << 20));          // 2 MB
    unsigned short* fnb   = (unsigned short*)(ws + (size_t)(4 << 20)); // 1 MB
    float*          sdot  = (float*)(ws + (size_t)(6 << 20));          // 32 KB
    float*          sims  = (float*)(ws + (size_t)(8 << 20));          // 32 MB

    hipMemsetAsync(d_out, 0, (size_t)out_size * sizeof(float), stream);
    prep_kernel<<<Bn, 256, 0, stream>>>(feat, mem0, targets, cams, fn, nrows, fnb);
    gemm_sims<<<NTOT / 64, 256, 0, stream>>>(mem0, fnb, sims);
    dots_kernel<<<Bn, 256, 0, stream>>>(fn, nrows, sdot);
    fused_kernel<<<Bn, 256, 0, stream>>>(sims, sdot, targets, out);
}